// Round 1
// baseline (406.500 us; speedup 1.0000x reference)
//
#include <hip/hip_runtime.h>

#define N_NODES 100000
#define NUM_TYPES 8
#define FACTOR 0.125f  // 1/sqrt(64)
#define NCOPY 8        // one accumulator copy per XCD (blockIdx & 7 ~ XCD id under
                       // round-robin dispatch; wrong mapping only costs locality)

// Single pass: grid-stride over edges, vectorized int4/float4 loads, fp32 HW
// atomics into an XCD-local copy of the output. 6.4M atomics over 100K nodes
// x 8 copies => ~8 edges/node/copy, negligible same-address contention, and
// each 400KB copy stays resident in its XCD's 4MB L2.
__global__ __launch_bounds__(256) void scatter_atomic_kernel(
    const int* __restrict__ centers,
    const int* __restrict__ neighbors,
    const float* __restrict__ eng,
    const int* __restrict__ atom_type,
    const float* __restrict__ scales,
    float* __restrict__ partial,   // [NCOPY][N_NODES]
    int E)
{
    __shared__ float s_scales[NUM_TYPES * NUM_TYPES];
    if (threadIdx.x < NUM_TYPES * NUM_TYPES) s_scales[threadIdx.x] = scales[threadIdx.x];
    __syncthreads();

    float* my = partial + (size_t)(blockIdx.x & (NCOPY - 1)) * N_NODES;

    const int n4 = E >> 2;
    const int stride = gridDim.x * blockDim.x;

    for (int i = blockIdx.x * blockDim.x + threadIdx.x; i < n4; i += stride) {
        int4   cc = ((const int4*)centers)[i];
        int4   nn = ((const int4*)neighbors)[i];
        float4 e  = ((const float4*)eng)[i];

        float v0 = e.x * s_scales[atom_type[cc.x] * NUM_TYPES + atom_type[nn.x]] * FACTOR;
        float v1 = e.y * s_scales[atom_type[cc.y] * NUM_TYPES + atom_type[nn.y]] * FACTOR;
        float v2 = e.z * s_scales[atom_type[cc.z] * NUM_TYPES + atom_type[nn.z]] * FACTOR;
        float v3 = e.w * s_scales[atom_type[cc.w] * NUM_TYPES + atom_type[nn.w]] * FACTOR;

        unsafeAtomicAdd(&my[cc.x], v0);
        unsafeAtomicAdd(&my[cc.y], v1);
        unsafeAtomicAdd(&my[cc.z], v2);
        unsafeAtomicAdd(&my[cc.w], v3);
    }

    // tail (E % 4) — dead for E = 6,400,000 but kept generic
    for (int i = (n4 << 2) + blockIdx.x * blockDim.x + threadIdx.x; i < E; i += stride) {
        int cn = centers[i];
        float v = eng[i] * s_scales[atom_type[cn] * NUM_TYPES + atom_type[neighbors[i]]] * FACTOR;
        unsafeAtomicAdd(&my[cn], v);
    }
}

// out[n] = sum over the 8 copies. 3.2 MB read (L2/L3-hot), 0.4 MB write.
__global__ __launch_bounds__(256) void reduce_copies_kernel(
    const float* __restrict__ partial, float* __restrict__ out)
{
    int n = blockIdx.x * blockDim.x + threadIdx.x;
    if (n >= N_NODES) return;
    float s = 0.0f;
#pragma unroll
    for (int k = 0; k < NCOPY; ++k) s += partial[(size_t)k * N_NODES + n];
    out[n] = s;
}

// Fallback (tiny workspace): direct atomic scatter into out.
__global__ __launch_bounds__(256) void edge_sum_atomic_kernel(
    const int* __restrict__ centers, const int* __restrict__ neighbors,
    const float* __restrict__ eng, const int* __restrict__ atom_type,
    const float* __restrict__ scales, float* __restrict__ out, int E)
{
    __shared__ float s_scales[NUM_TYPES * NUM_TYPES];
    if (threadIdx.x < NUM_TYPES * NUM_TYPES) s_scales[threadIdx.x] = scales[threadIdx.x];
    __syncthreads();
    int tid = blockIdx.x * blockDim.x + threadIdx.x;
    int stride = gridDim.x * blockDim.x;
    for (int i = tid; i < E; i += stride) {
        int cn = centers[i];
        float v = eng[i] * s_scales[atom_type[cn] * NUM_TYPES + atom_type[neighbors[i]]] * FACTOR;
        unsafeAtomicAdd(&out[cn], v);
    }
}

extern "C" void kernel_launch(void* const* d_in, const int* in_sizes, int n_in,
                              void* d_out, int out_size, void* d_ws, size_t ws_size,
                              hipStream_t stream) {
    const int E = in_sizes[1];  // edge_eng element count
    const int* edge_index = (const int*)d_in[0];   // [2, E]
    const float* edge_eng = (const float*)d_in[1]; // [E, 1]
    const int* atom_type = (const int*)d_in[2];    // [N, 1]
    const float* scales = (const float*)d_in[3];   // [T, T]
    float* out = (float*)d_out;

    const int* centers = edge_index;
    const int* neighbors = edge_index + E;

    const size_t ws_needed = (size_t)NCOPY * N_NODES * sizeof(float);  // 3.2 MB

    if (ws_size >= ws_needed) {
        float* partial = (float*)d_ws;
        hipMemsetAsync(partial, 0, ws_needed, stream);
        // 2048 blocks x 256 = full residency (8192 waves); ~3 int4-quads/thread.
        scatter_atomic_kernel<<<2048, 256, 0, stream>>>(
            centers, neighbors, edge_eng, atom_type, scales, partial, E);
        reduce_copies_kernel<<<(N_NODES + 255) / 256, 256, 0, stream>>>(partial, out);
    } else {
        hipMemsetAsync(d_out, 0, (size_t)out_size * sizeof(float), stream);
        edge_sum_atomic_kernel<<<2048, 256, 0, stream>>>(
            centers, neighbors, edge_eng, atom_type, scales, out, E);
    }
}

// Round 2
// 205.673 us; speedup vs baseline: 1.9764x; 1.9764x over previous
//
#include <hip/hip_runtime.h>

#define N_NODES 100000
#define NUM_TYPES 8
#define FACTOR 0.125f  // 1/sqrt(64)

#define S_CHUNK 16128              // nodes per chunk; 16128*4B = 63 KB LDS bins
#define C_CHUNKS 7                 // ceil(100000 / 16128) = 7
#define B_MAX 73                   // segments per chunk -> grid = 7*73 = 511 blocks (~2/CU)

// Kernel 1 (pre-pass): val[i] = eng[i] * scales[type[c], type[n]] * FACTOR.
// atom_type staged in LDS as u8 (100 KB) so the 2 random gathers/edge become
// near-free ds_read_u8 instead of 12.8M L2 transactions.
__global__ __launch_bounds__(1024) void edge_val_kernel(
    const int* __restrict__ centers,
    const int* __restrict__ neighbors,
    const float* __restrict__ eng,
    const int* __restrict__ atom_type,
    const float* __restrict__ scales,
    float* __restrict__ vals,
    int E, int N)
{
    __shared__ unsigned char s_type[N_NODES];
    __shared__ float s_scales[NUM_TYPES * NUM_TYPES];

    if (threadIdx.x < NUM_TYPES * NUM_TYPES)
        s_scales[threadIdx.x] = scales[threadIdx.x] * FACTOR;  // fold FACTOR
    for (int j = threadIdx.x; j < N; j += blockDim.x)
        s_type[j] = (unsigned char)atom_type[j];
    __syncthreads();

    const int n4 = E >> 2;
    const int stride = gridDim.x * blockDim.x;

    for (int i = blockIdx.x * blockDim.x + threadIdx.x; i < n4; i += stride) {
        int4   cc = ((const int4*)centers)[i];
        int4   nn = ((const int4*)neighbors)[i];
        float4 e  = ((const float4*)eng)[i];
        float4 v;
        v.x = e.x * s_scales[s_type[cc.x] * NUM_TYPES + s_type[nn.x]];
        v.y = e.y * s_scales[s_type[cc.y] * NUM_TYPES + s_type[nn.y]];
        v.z = e.z * s_scales[s_type[cc.z] * NUM_TYPES + s_type[nn.z]];
        v.w = e.w * s_scales[s_type[cc.w] * NUM_TYPES + s_type[nn.w]];
        ((float4*)vals)[i] = v;
    }
    // tail (E % 4)
    for (int i = (n4 << 2) + blockIdx.x * blockDim.x + threadIdx.x; i < E; i += stride)
        vals[i] = eng[i] * s_scales[s_type[centers[i]] * NUM_TYPES + s_type[neighbors[i]]];
}

// Kernel 2: block (c,b) scans edge-segment b of (centers, vals) only — 51.2 MB
// hot set, L3-resident across the 7 chunk passes. LDS-bin accumulate, dump to ws.
__global__ __launch_bounds__(512) void chunk_sum_kernel(
    const int* __restrict__ centers,
    const float* __restrict__ vals,
    float* __restrict__ ws,
    int E, int B)
{
    __shared__ float bins[S_CHUNK];

    const int c = blockIdx.x / B;   // chunk index
    const int b = blockIdx.x % B;   // edge-segment index

    for (int j = threadIdx.x; j < S_CHUNK; j += blockDim.x) bins[j] = 0.0f;
    __syncthreads();

    const int base = c * S_CHUNK;
    const int n4 = E >> 2;

    for (int i = b * blockDim.x + threadIdx.x; i < n4; i += B * blockDim.x) {
        int4   cc = ((const int4*)centers)[i];
        float4 v  = ((const float4*)vals)[i];

        unsigned j0 = (unsigned)(cc.x - base);
        unsigned j1 = (unsigned)(cc.y - base);
        unsigned j2 = (unsigned)(cc.z - base);
        unsigned j3 = (unsigned)(cc.w - base);

        if (j0 < S_CHUNK) atomicAdd(&bins[j0], v.x);
        if (j1 < S_CHUNK) atomicAdd(&bins[j1], v.y);
        if (j2 < S_CHUNK) atomicAdd(&bins[j2], v.z);
        if (j3 < S_CHUNK) atomicAdd(&bins[j3], v.w);
    }

    // tail (E % 4) — dead for E = 6,400,000; handled by segment b==0 of each chunk
    if (b == 0) {
        for (int i = (n4 << 2) + (int)threadIdx.x; i < E; i += blockDim.x) {
            unsigned j = (unsigned)(centers[i] - base);
            if (j < S_CHUNK) atomicAdd(&bins[j], vals[i]);
        }
    }

    __syncthreads();
    float* dst = ws + ((size_t)c * B + b) * S_CHUNK;
    for (int j = threadIdx.x; j < S_CHUNK; j += blockDim.x) dst[j] = bins[j];
}

// Kernel 3: out[n] = sum over B segment-partials of node n's chunk.
__global__ __launch_bounds__(256) void reduce_chunks_kernel(
    const float* __restrict__ ws, float* __restrict__ out, int B, int N)
{
    int n = blockIdx.x * blockDim.x + threadIdx.x;
    if (n >= N) return;
    int c = n / S_CHUNK;
    int j = n - c * S_CHUNK;
    const float* p = ws + (size_t)c * B * S_CHUNK + j;
    float s = 0.0f;
    for (int b = 0; b < B; ++b) s += p[(size_t)b * S_CHUNK];
    out[n] = s;
}

// Fallback (tiny workspace only): direct atomic scatter into out.
__global__ __launch_bounds__(256) void edge_sum_atomic_kernel(
    const int* __restrict__ centers, const int* __restrict__ neighbors,
    const float* __restrict__ eng, const int* __restrict__ atom_type,
    const float* __restrict__ scales, float* __restrict__ out, int E)
{
    __shared__ float s_scales[NUM_TYPES * NUM_TYPES];
    if (threadIdx.x < NUM_TYPES * NUM_TYPES) s_scales[threadIdx.x] = scales[threadIdx.x];
    __syncthreads();
    int tid = blockIdx.x * blockDim.x + threadIdx.x;
    int stride = gridDim.x * blockDim.x;
    for (int i = tid; i < E; i += stride) {
        int cn = centers[i];
        float v = eng[i] * s_scales[atom_type[cn] * NUM_TYPES + atom_type[neighbors[i]]] * FACTOR;
        unsafeAtomicAdd(&out[cn], v);
    }
}

extern "C" void kernel_launch(void* const* d_in, const int* in_sizes, int n_in,
                              void* d_out, int out_size, void* d_ws, size_t ws_size,
                              hipStream_t stream) {
    const int E = in_sizes[1];  // edge_eng element count
    const int N = in_sizes[2];  // atom_type element count
    const int* edge_index = (const int*)d_in[0];   // [2, E]
    const float* edge_eng = (const float*)d_in[1]; // [E, 1]
    const int* atom_type = (const int*)d_in[2];    // [N, 1]
    const float* scales = (const float*)d_in[3];   // [T, T]
    float* out = (float*)d_out;

    const int* centers = edge_index;
    const int* neighbors = edge_index + E;

    // ws layout: [vals: E floats (256B-aligned)] [partials: C*B*S_CHUNK floats]
    size_t vals_pad = ((size_t)E * sizeof(float) + 255) & ~(size_t)255;
    size_t per_b = (size_t)C_CHUNKS * S_CHUNK * sizeof(float);  // 451.6 KB per B

    int B = 0;
    if (N <= N_NODES && ws_size > vals_pad)
        B = (int)((ws_size - vals_pad) / per_b);
    if (B > B_MAX) B = B_MAX;

    if (B >= 4) {
        float* vals = (float*)d_ws;
        float* partial = (float*)((char*)d_ws + vals_pad);
        edge_val_kernel<<<256, 1024, 0, stream>>>(
            centers, neighbors, edge_eng, atom_type, scales, vals, E, N);
        chunk_sum_kernel<<<C_CHUNKS * B, 512, 0, stream>>>(
            centers, vals, partial, E, B);
        reduce_chunks_kernel<<<(N + 255) / 256, 256, 0, stream>>>(partial, out, B, N);
    } else {
        hipMemsetAsync(d_out, 0, (size_t)out_size * sizeof(float), stream);
        edge_sum_atomic_kernel<<<2048, 256, 0, stream>>>(
            centers, neighbors, edge_eng, atom_type, scales, out, E);
    }
}